// Round 8
// baseline (219.585 us; speedup 1.0000x reference)
//
#include <hip/hip_runtime.h>

#define DEV __device__ __forceinline__

typedef _Float16 f16;
typedef __attribute__((ext_vector_type(2))) _Float16 f16x2;
typedef __attribute__((ext_vector_type(4))) _Float16 f16x4;
typedef __attribute__((ext_vector_type(8))) _Float16 f16x8;
typedef __attribute__((ext_vector_type(4))) float f32x4;
typedef __attribute__((ext_vector_type(16))) float f32x16;
typedef __attribute__((ext_vector_type(4))) int i32x4;

constexpr int B = 2, T = 2048, D = 1024, H = 16, DH = 64;
constexpr int M = B * T;  // 4096
constexpr float LOG2E = 1.4426950408889634f;

DEV void gload_lds16(const void* g, void* l) {
  __builtin_amdgcn_global_load_lds(
      (const __attribute__((address_space(1))) void*)g,
      (__attribute__((address_space(3))) void*)l, 16, 0, 0);
}

DEV unsigned pack_pk(float a, float b) {
  auto v = __builtin_amdgcn_cvt_pkrtz(a, b);
  return __builtin_bit_cast(unsigned, v);
}

DEV float max3f(float a, float b, float c) { return fmaxf(fmaxf(a, b), c); }

DEV float sum16(const f32x16& v) {
  float a = (v[0] + v[1]) + (v[2] + v[3]);
  float b = (v[4] + v[5]) + (v[6] + v[7]);
  float c = (v[8] + v[9]) + (v[10] + v[11]);
  float d = (v[12] + v[13]) + (v[14] + v[15]);
  return (a + b) + (c + d);
}

#if __has_builtin(__builtin_amdgcn_permlane32_swap)
#define HAVE_PLSWAP 1
DEV void swap32(unsigned& a, unsigned& b) {
  auto r = __builtin_amdgcn_permlane32_swap((int)a, (int)b, false, false);
  a = (unsigned)r[0];
  b = (unsigned)r[1];
}
DEV float redmax32(float x) {
  unsigned a = __builtin_bit_cast(unsigned, x), b = a;
  swap32(a, b);
  return fmaxf(__builtin_bit_cast(float, a), __builtin_bit_cast(float, b));
}
DEV float redsum32(float x) {
  unsigned a = __builtin_bit_cast(unsigned, x), b = a;
  swap32(a, b);
  return __builtin_bit_cast(float, a) + __builtin_bit_cast(float, b);
}
#else
#define HAVE_PLSWAP 0
DEV float redmax32(float x) { return fmaxf(x, __shfl_xor(x, 32, 64)); }
DEV float redsum32(float x) { return x + __shfl_xor(x, 32, 64); }
#endif

// ---------------- cast f32 -> f16 ----------------
__global__ __launch_bounds__(256) void cast_f32_f16(
    const float* __restrict__ in, f16* __restrict__ out, int n) {
  int i = (blockIdx.x * 256 + threadIdx.x) * 8;
  if (i >= n) return;
  f32x4 a = *(const f32x4*)(in + i);
  f32x4 b = *(const f32x4*)(in + i + 4);
  f16x8 o;
  o[0] = (f16)a[0]; o[1] = (f16)a[1]; o[2] = (f16)a[2]; o[3] = (f16)a[3];
  o[4] = (f16)b[0]; o[5] = (f16)b[1]; o[6] = (f16)b[2]; o[7] = (f16)b[3];
  *(f16x8*)(out + i) = o;
}

// ---------------- transpose + cast W -> WT (WT[n][k] = W[k][n]) ----------------
__global__ __launch_bounds__(256) void transpose_cast(
    const float* __restrict__ Wq, const float* __restrict__ Wk,
    const float* __restrict__ Wv, f16* __restrict__ WT) {
  int mat = blockIdx.z;
  const float* W = (mat == 0) ? Wq : (mat == 1 ? Wk : Wv);
  f16* out = WT + (size_t)mat * D * D;
  __shared__ float tile[32][33];
  int nt = blockIdx.x * 32, kt = blockIdx.y * 32;
  int tx = threadIdx.x, ty = threadIdx.y;
  for (int j = 0; j < 4; ++j) {
    int r = ty + 8 * j;
    tile[r][tx] = W[(size_t)(kt + r) * D + nt + tx];
  }
  __syncthreads();
  for (int j = 0; j < 4; ++j) {
    int r = ty + 8 * j;
    out[(size_t)(nt + r) * D + kt + tx] = (f16)tile[tx][r];
  }
}

// ---------------- QKV projection GEMM ----------------
// Q,K out: head-blocked [(b*H+h)][t][64]; V out: transposed [(b*H+h)][d][t].
__global__ __launch_bounds__(256) void qkv_gemm(
    const f16* __restrict__ XQ, const f16* __restrict__ XK,
    const f16* __restrict__ WT, const float* __restrict__ bq,
    const float* __restrict__ bk, const float* __restrict__ bv,
    f16* __restrict__ QKV) {
  int mat = blockIdx.z;
  const f16* X = (mat == 0) ? XQ : XK;
  const f16* Wt = WT + (size_t)mat * D * D;
  const float* bias = (mat == 0) ? bq : (mat == 1 ? bk : bv);
  f16* out = QKV + (size_t)mat * M * D;
  float oscale = (mat == 0) ? 0.125f * LOG2E : 1.0f;
  int Lb = blockIdx.x + 8 * blockIdx.y;  // 0..255
  int n0 = (Lb & 7) * 128, m0 = (Lb >> 3) * 128;

  __shared__ f16 lA[128 * 64];
  __shared__ f16 lB[128 * 64];
  char* lAb = (char*)lA;
  char* lBb = (char*)lB;

  int tid = threadIdx.x;
  int w = tid >> 6, lane = tid & 63;
  int l15 = lane & 15, lhi = lane >> 4;
  int wr = w >> 1, wc = w & 1;
  int r8 = lane >> 3, slot = lane & 7;
  int sslot = slot ^ r8;

  f32x4 acc[4][4] = {};

  for (int kt = 0; kt < D / 64; ++kt) {
    __syncthreads();
    for (int i = 0; i < 4; ++i) {
      int chunk = w * 4 + i;
      int row = chunk * 8 + r8;
      const f16* srcA = X + (size_t)(m0 + row) * D + kt * 64 + sslot * 8;
      gload_lds16(srcA, lAb + chunk * 1024);
      const f16* srcB = Wt + (size_t)(n0 + row) * D + kt * 64 + sslot * 8;
      gload_lds16(srcB, lBb + chunk * 1024);
    }
    __syncthreads();
    for (int ks = 0; ks < 2; ++ks) {
      f16x8 aF[4], bF[4];
      for (int mt = 0; mt < 4; ++mt) {
        int row = wr * 64 + mt * 16 + l15;
        int byt = (row * 128 + ks * 64 + lhi * 16) ^ ((row & 7) << 4);
        aF[mt] = *(const f16x8*)(lAb + byt);
      }
      for (int nt = 0; nt < 4; ++nt) {
        int row = wc * 64 + nt * 16 + l15;
        int byt = (row * 128 + ks * 64 + lhi * 16) ^ ((row & 7) << 4);
        bF[nt] = *(const f16x8*)(lBb + byt);
      }
      for (int mt = 0; mt < 4; ++mt)
        for (int nt = 0; nt < 4; ++nt)
          acc[mt][nt] = __builtin_amdgcn_mfma_f32_16x16x32_f16(
              aF[mt], bF[nt], acc[mt][nt], 0, 0, 0);
    }
  }

  float bv4[4];
  for (int nt = 0; nt < 4; ++nt) bv4[nt] = bias[n0 + wc * 64 + nt * 16 + l15];
  if (mat < 2) {
    for (int mt = 0; mt < 4; ++mt)
      for (int nt = 0; nt < 4; ++nt) {
        int col = n0 + wc * 64 + nt * 16 + l15;
        int hh = col >> 6, dh = col & 63;
        for (int r = 0; r < 4; ++r) {
          int row = m0 + wr * 64 + mt * 16 + lhi * 4 + r;
          int bb = row >> 11, tt = row & (T - 1);
          out[((size_t)(bb * H + hh) * T + tt) * 64 + dh] =
              (f16)((acc[mt][nt][r] + bv4[nt]) * oscale);
        }
      }
  } else {
    for (int mt = 0; mt < 4; ++mt)
      for (int nt = 0; nt < 4; ++nt) {
        int col = n0 + wc * 64 + nt * 16 + l15;
        int hh = col >> 6, dh = col & 63;
        int row0 = m0 + wr * 64 + mt * 16 + lhi * 4;
        int bb = row0 >> 11, tt = row0 & (T - 1);
        f16x4 pk;
        for (int r = 0; r < 4; ++r) pk[r] = (f16)(acc[mt][nt][r] + bv4[nt]);
        *(f16x4*)(out + ((size_t)(bb * H + hh) * 64 + dh) * T + tt) = pk;
      }
  }
}

// ---------------- fused flash attention ----------------
// 512 blocks (XCD-swizzled), 4 waves; wave w: q rows [w*32,w*32+32).
// Swapped QK^T; P in registers; PV deferred one tile (MFMA/VALU overlap).
__global__ __launch_bounds__(256) void attn(
    const f16* __restrict__ QKV, const float* __restrict__ mask,
    const int* __restrict__ mfp, float* __restrict__ out) {
  int L = blockIdx.x + 16 * blockIdx.y + 256 * blockIdx.z;  // 0..511
  int e = L & 7, q = L >> 3;          // e = XCD
  int bh = e * 4 + (q & 3);           // 4 (b,h) pairs per XCD -> K/V L2-hot
  int q0 = (q >> 2) * 128;
  int b = bh >> 4, h = bh & 15;
  int mf = *mfp;
  constexpr int NT = T / 64;

  const f16* Qh = QKV + (size_t)bh * T * 64;
  const f16* Kh = QKV + (size_t)M * D + (size_t)bh * T * 64;
  const f16* VTh = QKV + (size_t)2 * M * D + (size_t)bh * 64 * T;

  __shared__ char smem[32768];  // [2]x8KB K | [2]x8KB VT ; reused as 32KB f32 O

  int tid = threadIdx.x;
  int w = tid >> 6, lane = tid & 63;
  int l31 = lane & 31, hi = lane >> 5;
  int qrow = q0 + w * 32 + l31;

  // per-wave mask nonzero scan (no LDS)
  const float* mb = mask + (size_t)b * T;
  bool lnz = false;
#pragma unroll
  for (int j = 0; j < 8; ++j) {
    f32x4 mv = *(const f32x4*)(mb + lane * 32 + j * 4);
    lnz |= (mv[0] != 0.f) | (mv[1] != 0.f) | (mv[2] != 0.f) | (mv[3] != 0.f);
  }
  int domask = __any(lnz) | mf;

  // Q fragments in registers
  f16x8 qF[4];
  const f16* qp = Qh + (size_t)qrow * 64;
#pragma unroll
  for (int kc = 0; kc < 4; ++kc) qF[kc] = *(const f16x8*)(qp + kc * 16 + hi * 8);

  auto STAGE = [&](int kv0, int buf) {
    char* dK = smem + buf * 8192;
    char* dV = smem + 16384 + buf * 8192;
#pragma unroll
    for (int i = 0; i < 2; ++i) {
      int c = (w * 2 + i) * 64 + lane;
      int r = c >> 3;
      int slot = (c & 7) ^ (r & 7);
      gload_lds16(Kh + (size_t)(kv0 + r) * 64 + slot * 8, dK + (w * 2 + i) * 1024);
      gload_lds16(VTh + (size_t)r * T + kv0 + slot * 8, dV + (w * 2 + i) * 1024);
    }
  };

  float mprev = -1e30f, lsum = 0.f;
  f32x16 oAcc[2] = {};
  f16x8 vA[8], vB[8], pA[4], pB[4];

  STAGE(0, 0);
  __syncthreads();

  // tile body: QK(t) -> [PV(t-1) from vPrev/pPrev] -> softmax(t) -> pCur; V(t)->vCur
  auto TILE = [&](int t, f16x8 (&vCur)[8], f16x8 (&vPrev)[8],
                  f16x8 (&pCur)[4], f16x8 (&pPrev)[4], bool doPV) {
    if (t) __syncthreads();
    if (t + 1 < NT) STAGE((t + 1) * 64, (t + 1) & 1);
    int kv0 = t * 64;
    const char* bK = smem + (t & 1) * 8192;
    const char* bV = smem + 16384 + (t & 1) * 8192;

    // V(t) -> registers (used next tile)
#pragma unroll
    for (int df = 0; df < 2; ++df)
#pragma unroll
      for (int kc = 0; kc < 4; ++kc) {
        int row = df * 32 + l31;
        vCur[df * 4 + kc] =
            *(const f16x8*)(bV + ((row * 128 + kc * 32 + hi * 16) ^ ((row & 7) << 4)));
      }

    // QK^T: S^T frags, lane owns q-row l31
    f32x16 sA[2] = {};
    __builtin_amdgcn_s_setprio(1);
#pragma unroll
    for (int f = 0; f < 2; ++f)
#pragma unroll
      for (int kc = 0; kc < 4; ++kc) {
        int row = f * 32 + l31;
        f16x8 kF =
            *(const f16x8*)(bK + ((row * 128 + kc * 32 + hi * 16) ^ ((row & 7) << 4)));
        sA[f] = __builtin_amdgcn_mfma_f32_32x32x16_f16(kF, qF[kc], sA[f], 0, 0, 0);
      }
    // PV(t-1): independent of QK(t) -> hides MFMA->VALU dependency
    if (doPV) {
#pragma unroll
      for (int df = 0; df < 2; ++df)
#pragma unroll
        for (int kc = 0; kc < 4; ++kc)
          oAcc[df] = __builtin_amdgcn_mfma_f32_32x32x16_f16(
              vPrev[df * 4 + kc], pPrev[kc], oAcc[df], 0, 0, 0);
    }
    __builtin_amdgcn_s_setprio(0);

    // mask + causal + row max
    float mx;
    if (domask) {
      mx = -1e30f;
#pragma unroll
      for (int f = 0; f < 2; ++f)
#pragma unroll
        for (int r = 0; r < 16; ++r) {
          int kv = kv0 + f * 32 + (r & 3) + 8 * (r >> 2) + 4 * hi;
          float v = sA[f][r] + LOG2E * mb[kv];
          if (mf && kv >= qrow) v = -1e30f;
          sA[f][r] = v;
          mx = fmaxf(mx, v);
        }
    } else {
      float t0 = max3f(sA[0][0], sA[0][1], sA[0][2]);
      float t1 = max3f(sA[0][3], sA[0][4], sA[0][5]);
      float t2 = max3f(sA[0][6], sA[0][7], sA[0][8]);
      float t3 = max3f(sA[0][9], sA[0][10], sA[0][11]);
      float t4 = max3f(sA[0][12], sA[0][13], sA[0][14]);
      float t5 = max3f(sA[1][0], sA[1][1], sA[1][2]);
      float t6 = max3f(sA[1][3], sA[1][4], sA[1][5]);
      float t7 = max3f(sA[1][6], sA[1][7], sA[1][8]);
      float t8 = max3f(sA[1][9], sA[1][10], sA[1][11]);
      float t9 = max3f(sA[1][12], sA[1][13], sA[1][14]);
      float u0 = max3f(t0, t1, t2);
      float u1 = max3f(t3, t4, sA[0][15]);
      float u2 = max3f(t5, t6, t7);
      float u3 = max3f(t8, t9, sA[1][15]);
      mx = fmaxf(max3f(u0, u1, u2), u3);
    }
    mx = redmax32(mx);

    // defer-max rescale (THR=8, log2 domain). PV(t-1) already in oAcc -> safe.
    if (!__all(mx <= mprev + 8.f)) {
      float mn = fmaxf(mprev, mx);
      float asc = __builtin_amdgcn_exp2f(mprev - mn);
      lsum *= asc;
#pragma unroll
      for (int f = 0; f < 2; ++f)
#pragma unroll
        for (int r = 0; r < 16; ++r) oAcc[f][r] *= asc;
      mprev = mn;
    }

    // exp2 + tree row-sum
#pragma unroll
    for (int f = 0; f < 2; ++f)
#pragma unroll
      for (int r = 0; r < 16; ++r)
        sA[f][r] = __builtin_amdgcn_exp2f(sA[f][r] - mprev);
    lsum += redsum32(sum16(sA[0]) + sum16(sA[1]));

    // P -> registers: pCur[kc][j] = P[q=l31][kv0 + kc*16 + hi*8 + j]
#if HAVE_PLSWAP
#pragma unroll
    for (int f = 0; f < 2; ++f)
#pragma unroll
      for (int half = 0; half < 2; ++half) {
        unsigned p0 = pack_pk(sA[f][half * 8 + 0], sA[f][half * 8 + 1]);
        unsigned p1 = pack_pk(sA[f][half * 8 + 2], sA[f][half * 8 + 3]);
        unsigned p2 = pack_pk(sA[f][half * 8 + 4], sA[f][half * 8 + 5]);
        unsigned p3 = pack_pk(sA[f][half * 8 + 6], sA[f][half * 8 + 7]);
        swap32(p0, p2);
        swap32(p1, p3);
        i32x4 d;
        d[0] = (int)p0; d[1] = (int)p1; d[2] = (int)p2; d[3] = (int)p3;
        pCur[f * 2 + half] = __builtin_bit_cast(f16x8, d);
      }
#else
#pragma unroll
    for (int f = 0; f < 2; ++f) {
      unsigned pk_[8], px_[8];
#pragma unroll
      for (int g = 0; g < 8; ++g) {
        pk_[g] = pack_pk(sA[f][2 * g], sA[f][2 * g + 1]);
        px_[g] = (unsigned)__shfl_xor((int)pk_[g], 32, 64);
      }
#pragma unroll
      for (int half = 0; half < 2; ++half) {
        int o = half * 4;
        i32x4 d;
        d[0] = (int)(hi ? px_[o + 2] : pk_[o + 0]);
        d[1] = (int)(hi ? px_[o + 3] : pk_[o + 1]);
        d[2] = (int)(hi ? pk_[o + 2] : px_[o + 0]);
        d[3] = (int)(hi ? pk_[o + 3] : px_[o + 1]);
        pCur[f * 2 + half] = __builtin_bit_cast(f16x8, d);
      }
    }
#endif
  };

  TILE(0, vA, vB, pA, pB, false);
  for (int t = 1; t + 1 < NT; t += 2) {
    TILE(t, vB, vA, pB, pA, true);
    TILE(t + 1, vA, vB, pA, pB, true);
  }
  TILE(NT - 1, vB, vA, pB, pA, true);  // NT even: last tile cur = vB/pB

  // final deferred PV (tile NT-1)
  __builtin_amdgcn_s_setprio(1);
#pragma unroll
  for (int df = 0; df < 2; ++df)
#pragma unroll
    for (int kc = 0; kc < 4; ++kc)
      oAcc[df] = __builtin_amdgcn_mfma_f32_32x32x16_f16(vB[df * 4 + kc], pB[kc],
                                                        oAcc[df], 0, 0, 0);
  __builtin_amdgcn_s_setprio(0);

  // ---- epilogue: O^T -> LDS (swizzled) -> coalesced rows to out [B,T,D] ----
  __syncthreads();  // all K/V reads done; smem free for O
  float linv = 1.0f / lsum;
  float* sOw = (float*)smem + w * 2048;  // [32 q][64 d], slot d' = d ^ q
#pragma unroll
  for (int df = 0; df < 2; ++df)
#pragma unroll
    for (int r = 0; r < 16; ++r) {
      int d = df * 32 + 4 * hi + (r & 3) + 8 * (r >> 2);
      sOw[l31 * 64 + (d ^ l31)] = oAcc[df][r] * linv;
    }
  __syncthreads();
  float* op0 = out + (size_t)(b * T + q0 + w * 32) * D + h * 64;
#pragma unroll
  for (int r2 = 0; r2 < 32; ++r2) {
    float v = sOw[r2 * 64 + (lane ^ r2)];
    op0[(size_t)r2 * D + lane] = v;
  }
}

extern "C" void kernel_launch(void* const* d_in, const int* in_sizes, int n_in,
                              void* d_out, int out_size, void* d_ws, size_t ws_size,
                              hipStream_t stream) {
  const float* q_in = (const float*)d_in[0];
  const float* k_in = (const float*)d_in[1];
  const float* amask = (const float*)d_in[2];
  const float* Wq = (const float*)d_in[3];
  const float* bq = (const float*)d_in[4];
  const float* Wk = (const float*)d_in[5];
  const float* bk = (const float*)d_in[6];
  const float* Wv = (const float*)d_in[7];
  const float* bv = (const float*)d_in[8];
  const int* mf = (const int*)d_in[9];
  float* out = (float*)d_out;

  char* ws = (char*)d_ws;
  f16* XQ = (f16*)ws;                            // 8 MB
  f16* XK = (f16*)(ws + (((size_t)8) << 20));    // 8 MB
  f16* WT = (f16*)(ws + (((size_t)16) << 20));   // 6 MB
  f16* QKV = (f16*)(ws + (((size_t)24) << 20));  // 24 MB (Q,K head-blocked; V transposed)

  cast_f32_f16<<<2048, 256, 0, stream>>>(q_in, XQ, M * D);
  cast_f32_f16<<<2048, 256, 0, stream>>>(k_in, XK, M * D);
  transpose_cast<<<dim3(32, 32, 3), dim3(32, 8), 0, stream>>>(Wq, Wk, Wv, WT);
  qkv_gemm<<<dim3(8, 32, 3), 256, 0, stream>>>(XQ, XK, WT, bq, bk, bv, QKV);
  attn<<<dim3(16, 16, 2), 256, 0, stream>>>(QKV, amask, mf, out);
}

// Round 9
// 203.533 us; speedup vs baseline: 1.0789x; 1.0789x over previous
//
#include <hip/hip_runtime.h>

#define DEV __device__ __forceinline__

typedef _Float16 f16;
typedef __attribute__((ext_vector_type(2))) _Float16 f16x2;
typedef __attribute__((ext_vector_type(4))) _Float16 f16x4;
typedef __attribute__((ext_vector_type(8))) _Float16 f16x8;
typedef __attribute__((ext_vector_type(4))) float f32x4;
typedef __attribute__((ext_vector_type(16))) float f32x16;
typedef __attribute__((ext_vector_type(4))) int i32x4;

constexpr int B = 2, T = 2048, D = 1024, H = 16, DH = 64;
constexpr int M = B * T;  // 4096
constexpr float LOG2E = 1.4426950408889634f;

DEV void gload_lds16(const void* g, void* l) {
  __builtin_amdgcn_global_load_lds(
      (const __attribute__((address_space(1))) void*)g,
      (__attribute__((address_space(3))) void*)l, 16, 0, 0);
}

DEV unsigned pack_pk(float a, float b) {
  auto v = __builtin_amdgcn_cvt_pkrtz(a, b);
  return __builtin_bit_cast(unsigned, v);
}

DEV float max3f(float a, float b, float c) { return fmaxf(fmaxf(a, b), c); }

#if __has_builtin(__builtin_amdgcn_permlane32_swap)
#define HAVE_PLSWAP 1
DEV void swap32(unsigned& a, unsigned& b) {
  auto r = __builtin_amdgcn_permlane32_swap((int)a, (int)b, false, false);
  a = (unsigned)r[0];
  b = (unsigned)r[1];
}
DEV float redmax32(float x) {
  unsigned a = __builtin_bit_cast(unsigned, x), b = a;
  swap32(a, b);
  return fmaxf(__builtin_bit_cast(float, a), __builtin_bit_cast(float, b));
}
DEV float redsum32(float x) {
  unsigned a = __builtin_bit_cast(unsigned, x), b = a;
  swap32(a, b);
  return __builtin_bit_cast(float, a) + __builtin_bit_cast(float, b);
}
#else
#define HAVE_PLSWAP 0
DEV float redmax32(float x) { return fmaxf(x, __shfl_xor(x, 32, 64)); }
DEV float redsum32(float x) { return x + __shfl_xor(x, 32, 64); }
#endif

// ---------------- fused cast f32 -> f16 (Q then K) ----------------
__global__ __launch_bounds__(256) void cast_qk(
    const float* __restrict__ qin, const float* __restrict__ kin,
    f16* __restrict__ outq) {
  int bi = blockIdx.x;
  const float* in = (bi < 2048) ? qin : kin;
  f16* out = outq + ((bi < 2048) ? 0 : (size_t)M * D);
  int i = ((bi & 2047) * 256 + threadIdx.x) * 8;
  f32x4 a = *(const f32x4*)(in + i);
  f32x4 b = *(const f32x4*)(in + i + 4);
  f16x8 o;
  o[0] = (f16)a[0]; o[1] = (f16)a[1]; o[2] = (f16)a[2]; o[3] = (f16)a[3];
  o[4] = (f16)b[0]; o[5] = (f16)b[1]; o[6] = (f16)b[2]; o[7] = (f16)b[3];
  *(f16x8*)(out + i) = o;
}

// ---------------- transpose + cast W -> WT (WT[n][k] = W[k][n]) ----------------
__global__ __launch_bounds__(256) void transpose_cast(
    const float* __restrict__ Wq, const float* __restrict__ Wk,
    const float* __restrict__ Wv, f16* __restrict__ WT) {
  int mat = blockIdx.z;
  const float* W = (mat == 0) ? Wq : (mat == 1 ? Wk : Wv);
  f16* out = WT + (size_t)mat * D * D;
  __shared__ float tile[32][33];
  int nt = blockIdx.x * 32, kt = blockIdx.y * 32;
  int tx = threadIdx.x, ty = threadIdx.y;
  for (int j = 0; j < 4; ++j) {
    int r = ty + 8 * j;
    tile[r][tx] = W[(size_t)(kt + r) * D + nt + tx];
  }
  __syncthreads();
  for (int j = 0; j < 4; ++j) {
    int r = ty + 8 * j;
    out[(size_t)(nt + r) * D + kt + tx] = (f16)tile[tx][r];
  }
}

// ---------------- QKV projection GEMM (double-buffered LDS) ----------------
// Q,K out: head-blocked [(b*H+h)][t][64]; V out: transposed [(b*H+h)][d][t].
__global__ __launch_bounds__(256) void qkv_gemm(
    const f16* __restrict__ XQ, const f16* __restrict__ XK,
    const f16* __restrict__ WT, const float* __restrict__ bq,
    const float* __restrict__ bk, const float* __restrict__ bv,
    f16* __restrict__ QKV) {
  int mat = blockIdx.z;
  const f16* X = (mat == 0) ? XQ : XK;
  const f16* Wt = WT + (size_t)mat * D * D;
  const float* bias = (mat == 0) ? bq : (mat == 1 ? bk : bv);
  f16* out = QKV + (size_t)mat * M * D;
  float oscale = (mat == 0) ? 0.125f * LOG2E : 1.0f;
  int Lb = blockIdx.x + 8 * blockIdx.y;  // 0..255
  int n0 = (Lb & 7) * 128, m0 = (Lb >> 3) * 128;

  __shared__ f16 lds[2 * 2 * 128 * 64];  // [buf][A|B][128][64]
  char* lAb = (char*)lds;                 // + buf*32768
  char* lBb = (char*)lds + 16384;

  int tid = threadIdx.x;
  int w = tid >> 6, lane = tid & 63;
  int l15 = lane & 15, lhi = lane >> 4;
  int wr = w >> 1, wc = w & 1;
  int r8 = lane >> 3, slot = lane & 7;
  int sslot = slot ^ r8;

  f32x4 acc[4][4] = {};
  constexpr int NKT = D / 64;  // 16

  auto STAGE = [&](int kt, int buf) {
#pragma unroll
    for (int i = 0; i < 4; ++i) {
      int chunk = w * 4 + i;
      int row = chunk * 8 + r8;
      gload_lds16(X + (size_t)(m0 + row) * D + kt * 64 + sslot * 8,
                  lAb + buf * 32768 + chunk * 1024);
      gload_lds16(Wt + (size_t)(n0 + row) * D + kt * 64 + sslot * 8,
                  lBb + buf * 32768 + chunk * 1024);
    }
  };

  STAGE(0, 0);
  __syncthreads();

  for (int kt = 0; kt < NKT; ++kt) {
    if (kt) __syncthreads();  // STAGE(kt) complete; reads of buf (kt-1)&1 done
    if (kt + 1 < NKT) STAGE(kt + 1, (kt + 1) & 1);
    const char* bA = lAb + (kt & 1) * 32768;
    const char* bB = lBb + (kt & 1) * 32768;
#pragma unroll
    for (int ks = 0; ks < 2; ++ks) {
      f16x8 aF[4], bF[4];
#pragma unroll
      for (int mt = 0; mt < 4; ++mt) {
        int row = wr * 64 + mt * 16 + l15;
        int byt = (row * 128 + ks * 64 + lhi * 16) ^ ((row & 7) << 4);
        aF[mt] = *(const f16x8*)(bA + byt);
      }
#pragma unroll
      for (int nt = 0; nt < 4; ++nt) {
        int row = wc * 64 + nt * 16 + l15;
        int byt = (row * 128 + ks * 64 + lhi * 16) ^ ((row & 7) << 4);
        bF[nt] = *(const f16x8*)(bB + byt);
      }
      __builtin_amdgcn_s_setprio(1);
#pragma unroll
      for (int mt = 0; mt < 4; ++mt)
#pragma unroll
        for (int nt = 0; nt < 4; ++nt)
          acc[mt][nt] = __builtin_amdgcn_mfma_f32_16x16x32_f16(
              aF[mt], bF[nt], acc[mt][nt], 0, 0, 0);
      __builtin_amdgcn_s_setprio(0);
    }
  }

  float bv4[4];
  for (int nt = 0; nt < 4; ++nt) bv4[nt] = bias[n0 + wc * 64 + nt * 16 + l15];
  if (mat < 2) {
    for (int mt = 0; mt < 4; ++mt)
      for (int nt = 0; nt < 4; ++nt) {
        int col = n0 + wc * 64 + nt * 16 + l15;
        int hh = col >> 6, dh = col & 63;
        for (int r = 0; r < 4; ++r) {
          int row = m0 + wr * 64 + mt * 16 + lhi * 4 + r;
          int bb = row >> 11, tt = row & (T - 1);
          out[((size_t)(bb * H + hh) * T + tt) * 64 + dh] =
              (f16)((acc[mt][nt][r] + bv4[nt]) * oscale);
        }
      }
  } else {
    for (int mt = 0; mt < 4; ++mt)
      for (int nt = 0; nt < 4; ++nt) {
        int col = n0 + wc * 64 + nt * 16 + l15;
        int hh = col >> 6, dh = col & 63;
        int row0 = m0 + wr * 64 + mt * 16 + lhi * 4;
        int bb = row0 >> 11, tt = row0 & (T - 1);
        f16x4 pk;
        for (int r = 0; r < 4; ++r) pk[r] = (f16)(acc[mt][nt][r] + bv4[nt]);
        *(f16x4*)(out + ((size_t)(bb * H + hh) * 64 + dh) * T + tt) = pk;
      }
  }
}

// ---------------- fused flash attention (R6 structure) ----------------
// 512 blocks (XCD-swizzled), 4 waves; wave w: q rows [w*32,w*32+32).
// Swapped QK^T (lane owns q-row); P in registers via cvt_pkrtz + permlane32_swap.
__global__ __launch_bounds__(256) void attn(
    const f16* __restrict__ QKV, const float* __restrict__ mask,
    const int* __restrict__ mfp, float* __restrict__ out) {
  int L = blockIdx.x + 16 * blockIdx.y + 256 * blockIdx.z;  // 0..511
  int e = L & 7, q = L >> 3;          // e = XCD
  int bh = e * 4 + (q & 3);           // 4 (b,h) pairs per XCD -> K/V L2-hot
  int q0 = (q >> 2) * 128;
  int b = bh >> 4, h = bh & 15;
  int mf = *mfp;
  constexpr int NT = T / 64;

  const f16* Qh = QKV + (size_t)bh * T * 64;
  const f16* Kh = QKV + (size_t)M * D + (size_t)bh * T * 64;
  const f16* VTh = QKV + (size_t)2 * M * D + (size_t)bh * 64 * T;

  __shared__ char smem[32768];  // [2]x8KB K | [2]x8KB VT ; reused as 32KB f32 O

  int tid = threadIdx.x;
  int w = tid >> 6, lane = tid & 63;
  int l31 = lane & 31, hi = lane >> 5;
  int qrow = q0 + w * 32 + l31;

  // per-wave mask nonzero scan (no LDS)
  const float* mb = mask + (size_t)b * T;
  bool lnz = false;
#pragma unroll
  for (int j = 0; j < 8; ++j) {
    f32x4 mv = *(const f32x4*)(mb + lane * 32 + j * 4);
    lnz |= (mv[0] != 0.f) | (mv[1] != 0.f) | (mv[2] != 0.f) | (mv[3] != 0.f);
  }
  int domask = __any(lnz) | mf;

  // Q fragments in registers
  f16x8 qF[4];
  const f16* qp = Qh + (size_t)qrow * 64;
#pragma unroll
  for (int kc = 0; kc < 4; ++kc) qF[kc] = *(const f16x8*)(qp + kc * 16 + hi * 8);

  auto STAGE = [&](int kv0, int buf) {
    char* dK = smem + buf * 8192;
    char* dV = smem + 16384 + buf * 8192;
#pragma unroll
    for (int i = 0; i < 2; ++i) {
      int c = (w * 2 + i) * 64 + lane;
      int r = c >> 3;
      int slot = (c & 7) ^ (r & 7);
      gload_lds16(Kh + (size_t)(kv0 + r) * 64 + slot * 8, dK + (w * 2 + i) * 1024);
      gload_lds16(VTh + (size_t)r * T + kv0 + slot * 8, dV + (w * 2 + i) * 1024);
    }
  };

  float mprev = -1e30f, lsum = 0.f;
  f32x16 oAcc[2] = {};
  STAGE(0, 0);
  __syncthreads();

  for (int t = 0; t < NT; ++t) {
    if (t) __syncthreads();
    if (t + 1 < NT) STAGE((t + 1) * 64, (t + 1) & 1);
    int kv0 = t * 64;
    const char* bK = smem + (t & 1) * 8192;
    const char* bV = smem + 16384 + (t & 1) * 8192;

    // QK^T: S^T frags, lane owns q-row l31
    f32x16 sA[2] = {};
    __builtin_amdgcn_s_setprio(1);
#pragma unroll
    for (int f = 0; f < 2; ++f)
#pragma unroll
      for (int kc = 0; kc < 4; ++kc) {
        int row = f * 32 + l31;
        f16x8 kF = *(const f16x8*)(bK + ((row * 128 + kc * 32 + hi * 16) ^ ((row & 7) << 4)));
        sA[f] = __builtin_amdgcn_mfma_f32_32x32x16_f16(kF, qF[kc], sA[f], 0, 0, 0);
      }
    __builtin_amdgcn_s_setprio(0);

    // mask + causal + row max
    float mx;
    if (domask) {
      mx = -1e30f;
#pragma unroll
      for (int f = 0; f < 2; ++f)
#pragma unroll
        for (int r = 0; r < 16; ++r) {
          int kv = kv0 + f * 32 + (r & 3) + 8 * (r >> 2) + 4 * hi;
          float v = sA[f][r] + LOG2E * mb[kv];
          if (mf && kv >= qrow) v = -1e30f;
          sA[f][r] = v;
          mx = fmaxf(mx, v);
        }
    } else {
      float t0 = max3f(sA[0][0], sA[0][1], sA[0][2]);
      float t1 = max3f(sA[0][3], sA[0][4], sA[0][5]);
      float t2 = max3f(sA[0][6], sA[0][7], sA[0][8]);
      float t3 = max3f(sA[0][9], sA[0][10], sA[0][11]);
      float t4 = max3f(sA[0][12], sA[0][13], sA[0][14]);
      float t5 = max3f(sA[1][0], sA[1][1], sA[1][2]);
      float t6 = max3f(sA[1][3], sA[1][4], sA[1][5]);
      float t7 = max3f(sA[1][6], sA[1][7], sA[1][8]);
      float t8 = max3f(sA[1][9], sA[1][10], sA[1][11]);
      float t9 = max3f(sA[1][12], sA[1][13], sA[1][14]);
      float u0 = max3f(t0, t1, t2);
      float u1 = max3f(t3, t4, sA[0][15]);
      float u2 = max3f(t5, t6, t7);
      float u3 = max3f(t8, t9, sA[1][15]);
      mx = fmaxf(max3f(u0, u1, u2), u3);
    }
    mx = redmax32(mx);

    // defer-max rescale (THR=8, log2 domain)
    if (!__all(mx <= mprev + 8.f)) {
      float mn = fmaxf(mprev, mx);
      float asc = __builtin_amdgcn_exp2f(mprev - mn);
      lsum *= asc;
#pragma unroll
      for (int f = 0; f < 2; ++f)
#pragma unroll
        for (int r = 0; r < 16; ++r) oAcc[f][r] *= asc;
      mprev = mn;
    }

    // exp2 + row sum
    float rs = 0.f;
#pragma unroll
    for (int f = 0; f < 2; ++f)
#pragma unroll
      for (int r = 0; r < 16; ++r) {
        float e2 = __builtin_amdgcn_exp2f(sA[f][r] - mprev);
        sA[f][r] = e2;
        rs += e2;
      }
    lsum += redsum32(rs);

    // P -> registers: need pF[kc][j] = P[q=l31][kv0 + kc*16 + hi*8 + j]
    f16x8 pF[4];
#if HAVE_PLSWAP
#pragma unroll
    for (int f = 0; f < 2; ++f)
#pragma unroll
      for (int half = 0; half < 2; ++half) {
        unsigned p0 = pack_pk(sA[f][half * 8 + 0], sA[f][half * 8 + 1]);
        unsigned p1 = pack_pk(sA[f][half * 8 + 2], sA[f][half * 8 + 3]);
        unsigned p2 = pack_pk(sA[f][half * 8 + 4], sA[f][half * 8 + 5]);
        unsigned p3 = pack_pk(sA[f][half * 8 + 6], sA[f][half * 8 + 7]);
        swap32(p0, p2);
        swap32(p1, p3);
        i32x4 d;
        d[0] = (int)p0; d[1] = (int)p1; d[2] = (int)p2; d[3] = (int)p3;
        pF[f * 2 + half] = __builtin_bit_cast(f16x8, d);
      }
#else
#pragma unroll
    for (int f = 0; f < 2; ++f) {
      unsigned pk_[8], px_[8];
#pragma unroll
      for (int g = 0; g < 8; ++g) {
        pk_[g] = pack_pk(sA[f][2 * g], sA[f][2 * g + 1]);
        px_[g] = (unsigned)__shfl_xor((int)pk_[g], 32, 64);
      }
#pragma unroll
      for (int half = 0; half < 2; ++half) {
        int o = half * 4;
        i32x4 d;
        d[0] = (int)(hi ? px_[o + 2] : pk_[o + 0]);
        d[1] = (int)(hi ? px_[o + 3] : pk_[o + 1]);
        d[2] = (int)(hi ? pk_[o + 2] : px_[o + 0]);
        d[3] = (int)(hi ? pk_[o + 3] : px_[o + 1]);
        pF[f * 2 + half] = __builtin_bit_cast(f16x8, d);
      }
    }
#endif

    // PV: O^T += mfma(VT frag, P frag)
    __builtin_amdgcn_s_setprio(1);
#pragma unroll
    for (int df = 0; df < 2; ++df)
#pragma unroll
      for (int kc = 0; kc < 4; ++kc) {
        int row = df * 32 + l31;
        f16x8 vF = *(const f16x8*)(bV + ((row * 128 + kc * 32 + hi * 16) ^ ((row & 7) << 4)));
        oAcc[df] = __builtin_amdgcn_mfma_f32_32x32x16_f16(vF, pF[kc], oAcc[df], 0, 0, 0);
      }
    __builtin_amdgcn_s_setprio(0);
  }

  // ---- epilogue: O^T -> LDS (swizzled) -> coalesced rows to out [B,T,D] ----
  __syncthreads();  // all K/V reads done; smem free for O
  float linv = 1.0f / lsum;
  float* sOw = (float*)smem + w * 2048;  // [32 q][64 d], slot d' = d ^ q
#pragma unroll
  for (int df = 0; df < 2; ++df)
#pragma unroll
    for (int r = 0; r < 16; ++r) {
      int d = df * 32 + 4 * hi + (r & 3) + 8 * (r >> 2);
      sOw[l31 * 64 + (d ^ l31)] = oAcc[df][r] * linv;
    }
  __syncthreads();
  float* op0 = out + (size_t)(b * T + q0 + w * 32) * D + h * 64;
#pragma unroll
  for (int r2 = 0; r2 < 32; ++r2) {
    float v = sOw[r2 * 64 + (lane ^ r2)];
    op0[(size_t)r2 * D + lane] = v;
  }
}

extern "C" void kernel_launch(void* const* d_in, const int* in_sizes, int n_in,
                              void* d_out, int out_size, void* d_ws, size_t ws_size,
                              hipStream_t stream) {
  const float* q_in = (const float*)d_in[0];
  const float* k_in = (const float*)d_in[1];
  const float* amask = (const float*)d_in[2];
  const float* Wq = (const float*)d_in[3];
  const float* bq = (const float*)d_in[4];
  const float* Wk = (const float*)d_in[5];
  const float* bk = (const float*)d_in[6];
  const float* Wv = (const float*)d_in[7];
  const float* bv = (const float*)d_in[8];
  const int* mf = (const int*)d_in[9];
  float* out = (float*)d_out;

  char* ws = (char*)d_ws;
  f16* XQK = (f16*)ws;                           // 16 MB (XQ then XK)
  f16* WT = (f16*)(ws + (((size_t)16) << 20));   // 6 MB
  f16* QKV = (f16*)(ws + (((size_t)24) << 20));  // 24 MB (Q,K head-blocked; V transposed)

  cast_qk<<<4096, 256, 0, stream>>>(q_in, k_in, XQK);
  transpose_cast<<<dim3(32, 32, 3), dim3(32, 8), 0, stream>>>(Wq, Wk, Wv, WT);
  qkv_gemm<<<dim3(8, 32, 3), 256, 0, stream>>>(XQK, XQK + (size_t)M * D, WT, bq,
                                               bk, bv, QKV);
  attn<<<dim3(16, 16, 2), 256, 0, stream>>>(QKV, amask, mf, out);
}